// Round 4
// baseline (672.695 us; speedup 1.0000x reference)
//
#include <hip/hip_runtime.h>
#include <cstdint>
#include <cstddef>

#define BB 128
#define TT 512
#define DD 100
#define HH 100
#define NG 400   // 4*H
#define LL 25
#define F_LOG2E 1.44269504088896340736f
#define F_LN2   0.69314718055994530942f

typedef __decltype(__builtin_amdgcn_cvt_pkrtz(0.f, 0.f)) h2_t;

__device__ __forceinline__ h2_t bc_h2(unsigned int u) {
  return __builtin_bit_cast(h2_t, u);
}
__device__ __forceinline__ unsigned int pk(float x, float y) {
  return __builtin_bit_cast(unsigned int, __builtin_amdgcn_cvt_pkrtz(x, y));
}

__device__ __forceinline__ float fdot2(h2_t a, h2_t b, float c) {
#if __has_builtin(__builtin_amdgcn_fdot2)
  return __builtin_amdgcn_fdot2(a, b, c, false);
#else
  return c + (float)a[0] * (float)b[0] + (float)a[1] * (float)b[1];
#endif
}

__device__ __forceinline__ float fexp2(float x) { return __builtin_amdgcn_exp2f(x); }
__device__ __forceinline__ float flog2(float x) { return __builtin_amdgcn_logf(x); }
__device__ __forceinline__ float frcp(float x)  { return __builtin_amdgcn_rcpf(x); }

__device__ __forceinline__ float sigmoid_f(float x) {
  return frcp(1.f + fexp2(-F_LOG2E * x));
}
__device__ __forceinline__ float tanh_f(float x) {
  float e = fexp2(2.f * F_LOG2E * x);
  return 1.f - 2.f * frcp(e + 1.f);
}

// quad all-reduce add via DPP (VALU pipe, no LDS latency).
// xor1 quad_perm [1,0,3,2] = 177; xor2 quad_perm [2,3,0,1] = 78.
template <int CTRL>
__device__ __forceinline__ float qadd(float v) {
#if __has_builtin(__builtin_amdgcn_mov_dpp)
  int m = __builtin_amdgcn_mov_dpp(__builtin_bit_cast(int, v), CTRL, 0xF, 0xF, true);
  return v + __builtin_bit_cast(float, m);
#else
  int x = (CTRL == 177) ? 1 : 2;
  return v + __shfl_xor(v, x);
#endif
}

// LDS-visibility-only barrier: drains lgkmcnt but leaves vmcnt free so global
// prefetch loads / em stores stay in flight across the barrier.
// imm 0xC07F: vmcnt=63, expcnt=7, lgkmcnt=0.
__device__ __forceinline__ void lds_barrier() {
  __builtin_amdgcn_s_waitcnt(0xC07F);
  __builtin_amdgcn_s_barrier();
}

// ---------------------------------------------------------------------------
// gin GEMM: gin[(b*2+dir)*512+t][p] = bias[r] + x[b,t]·W_ih[r,:], with
// r = (p&3)*100 + (p>>2) so scan thread tid reads position tid directly.
// ---------------------------------------------------------------------------
__global__ __launch_bounds__(448, 2) void gin_gemm2(
    const int* __restrict__ tok, const float* __restrict__ emb,
    const float* __restrict__ w_ih_f, const float* __restrict__ b_ih_f,
    const float* __restrict__ b_hh_f,
    const float* __restrict__ w_ih_b, const float* __restrict__ b_ih_b,
    const float* __restrict__ b_hh_b,
    unsigned short* __restrict__ gin16)
{
  const int tid  = threadIdx.x;
  const int tile = blockIdx.x & 511;
  const int dir  = blockIdx.x >> 9;
  const size_t m0 = (size_t)tile * 128;
  const int b  = (int)(m0 >> 9);
  const int t0 = (int)(m0 & 511);

  const float* w_ih = dir ? w_ih_b : w_ih_f;
  const float* b_ih = dir ? b_ih_b : b_ih_f;
  const float* b_hh = dir ? b_hh_b : b_hh_f;

  __shared__ __align__(16) unsigned int xs[128 * 52];

  for (int i = tid; i < 128 * 32; i += 448) {
    int r = i >> 5, q = i & 31;
    if (q < 25) {
      int tk = tok[m0 + r];
      float4 v = ((const float4*)(emb + (size_t)tk * DD))[q];
      xs[r * 52 + 2 * q]     = pk(v.x, v.y);
      xs[r * 52 + 2 * q + 1] = pk(v.z, v.w);
    }
  }

  const bool act = tid < NG;
  const int r0 = (tid & 3) * 100 + (tid >> 2);
  h2_t w0[50];
  float bias = 0.f;
  if (act) {
    const float4* wr = (const float4*)(w_ih + (size_t)r0 * DD);
#pragma unroll
    for (int kk = 0; kk < 25; ++kk) {
      float4 a = wr[kk];
      w0[2 * kk]     = __builtin_amdgcn_cvt_pkrtz(a.x, a.y);
      w0[2 * kk + 1] = __builtin_amdgcn_cvt_pkrtz(a.z, a.w);
    }
    bias = b_ih[r0] + b_hh[r0];
  }
  __syncthreads();

  if (act) {
    unsigned short* op = gin16 + ((size_t)(b * 2 + dir) * TT + t0) * NG + tid;
    for (int r = 0; r < 128; ++r) {
      const unsigned int* xr = xs + r * 52;
      float a0 = bias, a1 = 0.f, a2 = 0.f, a3 = 0.f;
#pragma unroll
      for (int g = 0; g < 12; ++g) {
        uint4 u = ((const uint4*)xr)[g];
        a0 = fdot2(w0[4 * g],     bc_h2(u.x), a0);
        a1 = fdot2(w0[4 * g + 1], bc_h2(u.y), a1);
        a2 = fdot2(w0[4 * g + 2], bc_h2(u.z), a2);
        a3 = fdot2(w0[4 * g + 3], bc_h2(u.w), a3);
      }
      a0 = fdot2(w0[48], bc_h2(xr[48]), a0);
      a1 = fdot2(w0[49], bc_h2(xr[49]), a1);
      *op = __builtin_bit_cast(unsigned short, (__fp16)((a0 + a1) + (a2 + a3)));
      op += NG;
    }
  }
}

// ---------------------------------------------------------------------------
// LSTM scan v4: one block per (batch, direction), 512 threads = 8 waves.
// Waves 0-6 (tid<400): thread = (unit j = tid>>2, K-slice s = tid&3).
//   Each lane computes partials for ALL 4 gates over its h-slice (14 fdot2
//   each, slices dword-offsets {0,12,24,36}, zero-padded to uniform 14),
//   quad all-reduce via DPP (no LDS), cell update computed redundantly in
//   all 4 lanes (bitwise identical), lane s==0 writes h (f16) to LDS.
// Wave 7 (tid>=448): 50 emission lanes compute em[t-1] = w_tag·h(t-1) from
//   the same LDS h (one step behind), store f32 to em_f / em_b. This
//   replaces the separate emissions kernel and the hc16 array entirely.
// gin prefetched 2 steps deep; in-loop barrier drains lgkmcnt only.
// ---------------------------------------------------------------------------
__global__ __launch_bounds__(512, 2) void lstm_scan4(
    const unsigned short* __restrict__ gin16,
    const float* __restrict__ w_hh_f, const float* __restrict__ w_hh_b,
    const float* __restrict__ w_tag, const float* __restrict__ b_tag,
    float* __restrict__ em_f, float* __restrict__ em_b)
{
  const int tid = threadIdx.x;
  const int b   = blockIdx.x & 127;
  const int dir = blockIdx.x >> 7;
  const float* w_hh = dir ? w_hh_b : w_hh_f;

  __shared__ __align__(16) unsigned int hls[2][52];

  const bool uact = tid < NG;
  const int j = tid >> 2;
  const int s = tid & 3;
  const int od = 12 * s;                  // h2-dword offset of this K-slice
  const int nn = (s == 3) ? 14 : 12;      // valid dwords in slice

  // --- unit-lane weights: 4 gates x 14 h2 (padded with zeros) ---
  h2_t wA[14], wB[14], wC[14], wD[14];
  if (uact) {
#pragma unroll
    for (int d = 0; d < 14; ++d) {
      int dd = (d < nn) ? (od + d) : 0;
      const float* r0 = w_hh + (size_t)(0 * 100 + j) * HH + 2 * dd;
      const float* r1 = w_hh + (size_t)(1 * 100 + j) * HH + 2 * dd;
      const float* r2 = w_hh + (size_t)(2 * 100 + j) * HH + 2 * dd;
      const float* r3 = w_hh + (size_t)(3 * 100 + j) * HH + 2 * dd;
      h2_t z = __builtin_amdgcn_cvt_pkrtz(0.f, 0.f);
      wA[d] = (d < nn) ? __builtin_amdgcn_cvt_pkrtz(r0[0], r0[1]) : z;
      wB[d] = (d < nn) ? __builtin_amdgcn_cvt_pkrtz(r1[0], r1[1]) : z;
      wC[d] = (d < nn) ? __builtin_amdgcn_cvt_pkrtz(r2[0], r2[1]) : z;
      wD[d] = (d < nn) ? __builtin_amdgcn_cvt_pkrtz(r3[0], r3[1]) : z;
    }
  }
  const float gm0 = (s == 0) ? 1.f : 0.f;
  const float gm1 = (s == 1) ? 1.f : 0.f;
  const float gm2 = (s == 2) ? 1.f : 0.f;
  const float gm3 = (s == 3) ? 1.f : 0.f;

  // --- emission-lane weights ---
  const int el = tid - 448;
  const bool eact = (el >= 0) && (el < 50);
  const int l  = (el >= 0) ? (el >> 1) : 0;
  const int hf = (el >= 0) ? (el & 1) : 0;
  const int eo = hf ? 24 : 0;             // h2-dword offset
  const int en = hf ? 26 : 24;            // valid dwords
  h2_t wt[26];
  float bt = 0.f;
  if (eact) {
    const float* wr = w_tag + (size_t)l * 200 + dir * 100;
#pragma unroll
    for (int d = 0; d < 26; ++d) {
      int dd = (d < en) ? (eo + d) : 0;
      h2_t z = __builtin_amdgcn_cvt_pkrtz(0.f, 0.f);
      wt[d] = (d < en) ? __builtin_amdgcn_cvt_pkrtz(wr[2 * dd], wr[2 * dd + 1]) : z;
    }
    if (dir == 0 && hf == 0) bt = b_tag[l];
  }
  float* emo = dir ? em_b : em_f;

  if (tid < 52) { hls[0][tid] = 0u; hls[1][tid] = 0u; }

  const unsigned short* gb = gin16 + (size_t)(b * 2 + dir) * TT * NG + tid;
  float c = 0.f;
  unsigned short g0 = 0, g1 = 0;
  if (uact) {
    g0 = gb[(size_t)(dir ? 511 : 0) * NG];
    g1 = gb[(size_t)(dir ? 510 : 1) * NG];
  }
  __syncthreads();

  for (int t = 0; t < TT; ++t) {
    if (uact) {
      // depth-2 gin prefetch
      int tn  = (t + 2 < TT) ? (t + 2) : (TT - 1);
      int ttn = dir ? (TT - 1 - tn) : tn;
      unsigned short g2 = gb[(size_t)ttn * NG];

      const unsigned int* hp = hls[t & 1] + od;
      uint4 u0 = *((const uint4*)hp);
      uint4 u1 = *((const uint4*)(hp + 4));
      uint4 u2 = *((const uint4*)(hp + 8));
      uint2 u3 = *((const uint2*)(hp + 12));
      unsigned int hv[14] = {u0.x, u0.y, u0.z, u0.w, u1.x, u1.y, u1.z, u1.w,
                             u2.x, u2.y, u2.z, u2.w, u3.x, u3.y};

      float gval = (float)__builtin_bit_cast(__fp16, g0);
      float p0 = gm0 * gval, p1 = gm1 * gval, p2 = gm2 * gval, p3 = gm3 * gval;
#pragma unroll
      for (int d = 0; d < 14; ++d) {
        h2_t h = bc_h2(hv[d]);
        p0 = fdot2(wA[d], h, p0);
        p1 = fdot2(wB[d], h, p1);
        p2 = fdot2(wC[d], h, p2);
        p3 = fdot2(wD[d], h, p3);
      }
      // quad all-reduce: every lane gets full i,f,g,o sums (bitwise identical)
      p0 = qadd<78>(qadd<177>(p0));
      p1 = qadd<78>(qadd<177>(p1));
      p2 = qadd<78>(qadd<177>(p2));
      p3 = qadd<78>(qadd<177>(p3));

      float iv = sigmoid_f(p0);
      float fv = sigmoid_f(p1);
      float gv = tanh_f(p2);
      float ov = sigmoid_f(p3);
      c = fmaf(fv, c, iv * gv);
      float hvv = ov * tanh_f(c);
      if (s == 0) ((__fp16*)(hls[(t + 1) & 1]))[j] = (__fp16)hvv;
      g0 = g1; g1 = g2;
    } else if (eact && t > 0) {
      const unsigned int* hp = hls[t & 1] + eo;
      uint4 e0 = *((const uint4*)hp);
      uint4 e1 = *((const uint4*)(hp + 4));
      uint4 e2 = *((const uint4*)(hp + 8));
      uint4 e3 = *((const uint4*)(hp + 12));
      uint4 e4 = *((const uint4*)(hp + 16));
      uint4 e5 = *((const uint4*)(hp + 20));
      uint2 e6 = *((const uint2*)(hp + 24));
      unsigned int ev[26] = {e0.x, e0.y, e0.z, e0.w, e1.x, e1.y, e1.z, e1.w,
                             e2.x, e2.y, e2.z, e2.w, e3.x, e3.y, e3.z, e3.w,
                             e4.x, e4.y, e4.z, e4.w, e5.x, e5.y, e5.z, e5.w,
                             e6.x, e6.y};
      float a0 = 0.f, a1 = 0.f, a2 = 0.f, a3 = 0.f;
#pragma unroll
      for (int d = 0; d < 26; ++d) {
        h2_t h = bc_h2(ev[d]);
        if ((d & 3) == 0) a0 = fdot2(wt[d], h, a0);
        else if ((d & 3) == 1) a1 = fdot2(wt[d], h, a1);
        else if ((d & 3) == 2) a2 = fdot2(wt[d], h, a2);
        else a3 = fdot2(wt[d], h, a3);
      }
      float ss = (a0 + a1) + (a2 + a3);
      float tot = qadd<177>(ss);   // pair (2l, 2l+1) in-quad sum
      if (hf == 0) {
        int tp = t - 1;
        int ttp = dir ? (TT - 1 - tp) : tp;
        emo[((size_t)b * TT + ttp) * LL + l] = tot + bt;
      }
    }
    lds_barrier();
  }

  // epilogue: emission for the last h (sits in hls[0] after 512 steps)
  if (eact) {
    const unsigned int* hp = hls[0] + eo;
    uint4 e0 = *((const uint4*)hp);
    uint4 e1 = *((const uint4*)(hp + 4));
    uint4 e2 = *((const uint4*)(hp + 8));
    uint4 e3 = *((const uint4*)(hp + 12));
    uint4 e4 = *((const uint4*)(hp + 16));
    uint4 e5 = *((const uint4*)(hp + 20));
    uint2 e6 = *((const uint2*)(hp + 24));
    unsigned int ev[26] = {e0.x, e0.y, e0.z, e0.w, e1.x, e1.y, e1.z, e1.w,
                           e2.x, e2.y, e2.z, e2.w, e3.x, e3.y, e3.z, e3.w,
                           e4.x, e4.y, e4.z, e4.w, e5.x, e5.y, e5.z, e5.w,
                           e6.x, e6.y};
    float a0 = 0.f, a1 = 0.f, a2 = 0.f, a3 = 0.f;
#pragma unroll
    for (int d = 0; d < 26; ++d) {
      h2_t h = bc_h2(ev[d]);
      if ((d & 3) == 0) a0 = fdot2(wt[d], h, a0);
      else if ((d & 3) == 1) a1 = fdot2(wt[d], h, a1);
      else if ((d & 3) == 2) a2 = fdot2(wt[d], h, a2);
      else a3 = fdot2(wt[d], h, a3);
    }
    float ss = (a0 + a1) + (a2 + a3);
    float tot = qadd<177>(ss);
    if (hf == 0) {
      int ttp = dir ? 0 : (TT - 1);
      emo[((size_t)b * TT + ttp) * LL + l] = tot + bt;
    }
  }
}

// ---------------------------------------------------------------------------
// FALLBACK scan (small ws): old structure, writes hc16 f16.
// ---------------------------------------------------------------------------
__global__ __launch_bounds__(512, 2) void lstm_scan_fb(
    const int* __restrict__ tok, const float* __restrict__ emb,
    const float* __restrict__ w_ih_f, const float* __restrict__ w_hh_f,
    const float* __restrict__ b_ih_f, const float* __restrict__ b_hh_f,
    const float* __restrict__ w_ih_b, const float* __restrict__ w_hh_b,
    const float* __restrict__ b_ih_b, const float* __restrict__ b_hh_b,
    unsigned short* __restrict__ hc16)
{
  const int tid = threadIdx.x;
  const int b   = blockIdx.x & 127;
  const int dir = blockIdx.x >> 7;

  const float* w_ih = dir ? w_ih_b : w_ih_f;
  const float* w_hh = dir ? w_hh_b : w_hh_f;
  const float* b_ih = dir ? b_ih_b : b_ih_f;
  const float* b_hh = dir ? b_hh_b : b_hh_f;

  __shared__ __align__(16) unsigned int xs[2][64];
  __shared__ __align__(16) unsigned int hls[64];
  __shared__ float gl[NG];

  h2_t wih[50], whh[50];
  float bias = 0.f;
  if (tid < NG) {
    const float4* wi = (const float4*)(w_ih + tid * DD);
    const float4* wh = (const float4*)(w_hh + tid * DD);
#pragma unroll
    for (int kk = 0; kk < 25; ++kk) {
      float4 a = wi[kk];
      wih[2 * kk]     = __builtin_amdgcn_cvt_pkrtz(a.x, a.y);
      wih[2 * kk + 1] = __builtin_amdgcn_cvt_pkrtz(a.z, a.w);
      float4 c = wh[kk];
      whh[2 * kk]     = __builtin_amdgcn_cvt_pkrtz(c.x, c.y);
      whh[2 * kk + 1] = __builtin_amdgcn_cvt_pkrtz(c.z, c.w);
    }
    bias = b_ih[tid] + b_hh[tid];
  }
  if (tid < 2) { xs[0][50 + tid] = 0u; xs[1][50 + tid] = 0u; hls[50 + tid] = 0u; }
  if (tid < 50) hls[tid] = 0u;

  const int base = b * TT;
  if (tid >= 448 && tid < 498) {
    int tt0 = dir ? (TT - 1) : 0;
    int i = tid - 448;
    int tk = tok[base + tt0];
    float2 v = ((const float2*)(emb + (size_t)tk * DD))[i];
    xs[0][i] = pk(v.x, v.y);
  }
  __syncthreads();

  float cst = 0.f;
  unsigned short* hcb = hc16 + (size_t)base * 200 + dir * 100;

  for (int t = 0; t < TT; ++t) {
    const int buf = t & 1;
    const int tt  = dir ? (TT - 1 - t) : t;

    if (tid < NG) {
      float a0 = bias, a1 = 0.f, a2 = 0.f, a3 = 0.f;
      const unsigned int* xp = xs[buf];
#pragma unroll
      for (int g = 0; g < 13; ++g) {
        uint4 u = ((const uint4*)xp)[g];
        const int k = 4 * g;
        a0 = fdot2(wih[k], bc_h2(u.x), a0);
        a1 = fdot2(wih[k + 1], bc_h2(u.y), a1);
        if (k + 2 < 50) a2 = fdot2(wih[k + 2], bc_h2(u.z), a2);
        if (k + 3 < 50) a3 = fdot2(wih[k + 3], bc_h2(u.w), a3);
      }
#pragma unroll
      for (int g = 0; g < 13; ++g) {
        uint4 u = ((const uint4*)hls)[g];
        const int k = 4 * g;
        a0 = fdot2(whh[k], bc_h2(u.x), a0);
        a1 = fdot2(whh[k + 1], bc_h2(u.y), a1);
        if (k + 2 < 50) a2 = fdot2(whh[k + 2], bc_h2(u.z), a2);
        if (k + 3 < 50) a3 = fdot2(whh[k + 3], bc_h2(u.w), a3);
      }
      float accs = (a0 + a1) + (a2 + a3);
      float av = (tid >= 200 && tid < 300) ? tanh_f(accs) : sigmoid_f(accs);
      gl[tid] = av;
    } else if (tid >= 448 && tid < 498 && t < TT - 1) {
      int ttn = dir ? (TT - 2 - t) : (t + 1);
      int i = tid - 448;
      int tk = tok[base + ttn];
      float2 v = ((const float2*)(emb + (size_t)tk * DD))[i];
      xs[buf ^ 1][i] = pk(v.x, v.y);
    }
    __syncthreads();

    if (tid < HH) {
      float gi = gl[tid], gf = gl[tid + 100], gg = gl[tid + 200], go = gl[tid + 300];
      cst = gf * cst + gi * gg;
      float hv = go * tanh_f(cst);
      __fp16 h16 = (__fp16)hv;
      ((__fp16*)hls)[tid] = h16;
      hcb[(size_t)tt * 200 + tid] = __builtin_bit_cast(unsigned short, h16);
    }
    __syncthreads();
  }
}

// Fallback emissions kernel (writes em_f with b_tag folded).
__global__ __launch_bounds__(256, 2) void emis2(
    const unsigned short* __restrict__ hc16, const float* __restrict__ w_tag,
    const float* __restrict__ b_tag, float* __restrict__ em)
{
  __shared__ unsigned int hsh[64 * 101];
  __shared__ unsigned int wsh[25 * 100];
  const int tid = threadIdx.x;
  const size_t m0 = (size_t)blockIdx.x * 64;

  const unsigned int* hcu = (const unsigned int*)hc16;
  for (int i = tid; i < 64 * 100; i += 256) {
    int r = i / 100;
    int k = i - r * 100;
    hsh[r * 101 + k] = hcu[m0 * 100 + i];
  }
  for (int i = tid; i < 25 * 100; i += 256) {
    float2 wv = ((const float2*)w_tag)[i];
    wsh[i] = pk(wv.x, wv.y);
  }
  __syncthreads();

  const int r = tid & 63, q = tid >> 6;
  int lidx[7];
  bool lv[7];
  float acc[7];
#pragma unroll
  for (int ii = 0; ii < 7; ++ii) {
    int l = q + 4 * ii;
    lv[ii] = (l < LL);
    lidx[ii] = lv[ii] ? l : 0;
    acc[ii] = lv[ii] ? b_tag[lidx[ii]] : 0.f;
  }
  const unsigned int* hrow = hsh + r * 101;
#pragma unroll 2
  for (int k = 0; k < 100; ++k) {
    h2_t hv = bc_h2(hrow[k]);
#pragma unroll
    for (int ii = 0; ii < 7; ++ii)
      acc[ii] = fdot2(hv, bc_h2(wsh[lidx[ii] * 100 + k]), acc[ii]);
  }
#pragma unroll
  for (int ii = 0; ii < 7; ++ii)
    if (lv[ii]) em[(m0 + r) * LL + lidx[ii]] = acc[ii];
}

// ---------------------------------------------------------------------------
// CRF: wave 0 = split partition scan (side 0 fwd t=0..255 / side 1 bwd
// t=511..256), full 25-source lse per lane (one bpermute window per step);
// wave 1 (side-0 blocks only) = gold path score, fully parallel.
// em = em_f + em_b.
// ---------------------------------------------------------------------------
__global__ __launch_bounds__(128) void crf_scan3(
    const float* __restrict__ em_f, const float* __restrict__ em_b,
    const int* __restrict__ tags, const int* __restrict__ lengths,
    const float* __restrict__ trans,
    const float* __restrict__ startt, const float* __restrict__ endt,
    float* __restrict__ ab, float* __restrict__ gold)
{
  const int tid  = threadIdx.x;
  const int b    = blockIdx.x >> 1;
  const int side = blockIdx.x & 1;

  if (tid < 64) {
    const int lane = tid;
    const int j = (lane < LL) ? lane : 0;
    const float* ef = em_f + (size_t)b * TT * LL;
    const float* eb = em_b + (size_t)b * TT * LL;

    float tc[LL];
#pragma unroll
    for (int i = 0; i < LL; ++i)
      tc[i] = (side == 0 ? trans[i * LL + j] : trans[j * LL + i]) * F_LOG2E;

    float a, C = 0.f;
    if (side == 0) {
      a = (startt[j] + ef[j] + eb[j]) * F_LOG2E;
      float efn = ef[LL + j], ebn = eb[LL + j];
      for (int t = 1; t < 256; ++t) {
        float emc = (efn + ebn) * F_LOG2E;
        int tn = (t + 1 < 256) ? t + 1 : t;
        efn = ef[(size_t)tn * LL + j];
        ebn = eb[(size_t)tn * LL + j];
        float sh = __shfl(a, 0);
        C += sh;
        float p0 = 0.f, p1 = 0.f, p2 = 0.f, p3 = 0.f;
#pragma unroll
        for (int i = 0; i < LL; ++i) {
          float ai = __shfl(a, i);
          float e = fexp2((ai - sh) + tc[i]);
          if ((i & 3) == 0) p0 += e; else if ((i & 3) == 1) p1 += e;
          else if ((i & 3) == 2) p2 += e; else p3 += e;
        }
        a = flog2((p0 + p1) + (p2 + p3)) + emc;
      }
    } else {
      a = endt[j] * F_LOG2E;
      float efn = ef[(size_t)(TT - 1) * LL + j], ebn = eb[(size_t)(TT - 1) * LL + j];
      for (int stp = 0; stp < 256; ++stp) {
        int t1 = TT - 1 - stp;
        float emc = (efn + ebn) * F_LOG2E;
        int t1n = (stp + 1 < 256) ? (t1 - 1) : t1;
        efn = ef[(size_t)t1n * LL + j];
        ebn = eb[(size_t)t1n * LL + j];
        float v = a + emc;
        float sh = __shfl(v, 0);
        C += sh;
        float p0 = 0.f, p1 = 0.f, p2 = 0.f, p3 = 0.f;
#pragma unroll
        for (int i = 0; i < LL; ++i) {
          float vi = __shfl(v, i);
          float e = fexp2((vi - sh) + tc[i]);
          if ((i & 3) == 0) p0 += e; else if ((i & 3) == 1) p1 += e;
          else if ((i & 3) == 2) p2 += e; else p3 += e;
        }
        a = flog2((p0 + p1) + (p2 + p3));
      }
    }
    if (lane < LL)
      ab[((size_t)b * 2 + side) * LL + lane] = (a + C) * F_LN2;
  } else if (side == 0) {
    const int lane = tid - 64;
    const int len = lengths[b];
    float acc = 0.f;
#pragma unroll
    for (int k = 0; k < 8; ++k) {
      int t = k * 64 + lane;
      int tg = tags[b * TT + t];
      size_t ei = ((size_t)b * TT + t) * LL + tg;
      float e = em_f[ei] + em_b[ei];
      float term;
      if (t == 0) term = startt[tg] + e;
      else        term = trans[tags[b * TT + t - 1] * LL + tg] + e;
      if (t == len - 1) term += endt[tg];
      if (t < len) acc += term;
    }
    for (int o = 32; o > 0; o >>= 1) acc += __shfl_down(acc, o);
    if (lane == 0) gold[b] = acc;
  }
}

// ---------------------------------------------------------------------------
// Final: logZ_b = lse(alpha+beta), out = sum_b (logZ_b - gold_b)
// ---------------------------------------------------------------------------
__global__ __launch_bounds__(128, 4) void crf_final(
    const float* __restrict__ ab, const float* __restrict__ gold,
    float* __restrict__ out)
{
  const int b = threadIdx.x;
  float v[LL];
  float m = -1e30f;
#pragma unroll
  for (int l = 0; l < LL; ++l) {
    v[l] = ab[((size_t)b * 2) * LL + l] + ab[((size_t)b * 2 + 1) * LL + l];
    m = fmaxf(m, v[l]);
  }
  float sacc = 0.f;
#pragma unroll
  for (int l = 0; l < LL; ++l) sacc += fexp2((v[l] - m) * F_LOG2E);
  float nll = (m + flog2(sacc) * F_LN2) - gold[b];

  for (int o = 32; o > 0; o >>= 1) nll += __shfl_down(nll, o);
  __shared__ float r2[2];
  if ((b & 63) == 0) r2[b >> 6] = nll;
  __syncthreads();
  if (b == 0) out[0] = r2[0] + r2[1];
}

extern "C" void kernel_launch(void* const* d_in, const int* in_sizes, int n_in,
                              void* d_out, int out_size, void* d_ws, size_t ws_size,
                              hipStream_t stream) {
  const int*   tok   = (const int*)d_in[0];
  const int*   tags  = (const int*)d_in[1];
  const int*   lens  = (const int*)d_in[2];
  const float* emb   = (const float*)d_in[3];
  const float* wif   = (const float*)d_in[4];
  const float* whf   = (const float*)d_in[5];
  const float* bif   = (const float*)d_in[6];
  const float* bhf   = (const float*)d_in[7];
  const float* wib   = (const float*)d_in[8];
  const float* whb   = (const float*)d_in[9];
  const float* bib   = (const float*)d_in[10];
  const float* bhb   = (const float*)d_in[11];
  const float* wtag  = (const float*)d_in[12];
  const float* btag  = (const float*)d_in[13];
  const float* trans = (const float*)d_in[14];
  const float* st    = (const float*)d_in[15];
  const float* en    = (const float*)d_in[16];

  char* wsb = (char*)d_ws;
  float* em_f = (float*)wsb;                                   //  6,553,600 B
  float* em_b = (float*)(wsb + 6553600);                       //  6,553,600 B
  float* gold = (float*)(wsb + 13107200);                      //        512 B
  float* ab   = (float*)(wsb + 13107712);                      //     25,600 B
  unsigned short* gin16 = (unsigned short*)(wsb + 13133312);   // 104,857,600 B
  const size_t need = 117990912ULL;

  if (ws_size >= need) {
    gin_gemm2<<<1024, 448, 0, stream>>>(tok, emb, wif, bif, bhf, wib, bib, bhb, gin16);
    lstm_scan4<<<256, 512, 0, stream>>>(gin16, whf, whb, wtag, btag, em_f, em_b);
  } else {
    // fallback: old pipeline, em_b zeroed
    unsigned short* hc16 = (unsigned short*)(wsb + 13133312);  // 26,214,400 B
    hipMemsetAsync(em_b, 0, 6553600, stream);
    lstm_scan_fb<<<256, 512, 0, stream>>>(tok, emb, wif, whf, bif, bhf,
                                          wib, whb, bib, bhb, hc16);
    emis2<<<1024, 256, 0, stream>>>(hc16, wtag, btag, em_f);
  }
  crf_scan3<<<256, 128, 0, stream>>>(em_f, em_b, tags, lens, trans, st, en, ab, gold);
  crf_final<<<1, 128, 0, stream>>>(ab, gold, (float*)d_out);
}

// Round 5
// 575.693 us; speedup vs baseline: 1.1685x; 1.1685x over previous
//
#include <hip/hip_runtime.h>
#include <cstdint>
#include <cstddef>

#define BB 128
#define TT 512
#define DD 100
#define HH 100
#define NG 400   // 4*H
#define LL 25
#define F_LOG2E 1.44269504088896340736f
#define F_LN2   0.69314718055994530942f

typedef __decltype(__builtin_amdgcn_cvt_pkrtz(0.f, 0.f)) h2_t;

__device__ __forceinline__ h2_t bc_h2(unsigned int u) {
  return __builtin_bit_cast(h2_t, u);
}
__device__ __forceinline__ unsigned int pk(float x, float y) {
  return __builtin_bit_cast(unsigned int, __builtin_amdgcn_cvt_pkrtz(x, y));
}

__device__ __forceinline__ float fdot2(h2_t a, h2_t b, float c) {
#if __has_builtin(__builtin_amdgcn_fdot2)
  return __builtin_amdgcn_fdot2(a, b, c, false);
#else
  return c + (float)a[0] * (float)b[0] + (float)a[1] * (float)b[1];
#endif
}

__device__ __forceinline__ float fexp2(float x) { return __builtin_amdgcn_exp2f(x); }
__device__ __forceinline__ float flog2(float x) { return __builtin_amdgcn_logf(x); }
__device__ __forceinline__ float frcp(float x)  { return __builtin_amdgcn_rcpf(x); }

__device__ __forceinline__ float sigmoid_f(float x) {
  return frcp(1.f + fexp2(-F_LOG2E * x));
}
__device__ __forceinline__ float tanh_f(float x) {
  float e = fexp2(2.f * F_LOG2E * x);
  return 1.f - 2.f * frcp(e + 1.f);
}

// quad all-reduce add via DPP. xor1 = quad_perm[1,0,3,2] = 177; xor2 = 78.
template <int CTRL>
__device__ __forceinline__ float qadd(float v) {
#if __has_builtin(__builtin_amdgcn_mov_dpp)
  int m = __builtin_amdgcn_mov_dpp(__builtin_bit_cast(int, v), CTRL, 0xF, 0xF, true);
  return v + __builtin_bit_cast(float, m);
#else
  int x = (CTRL == 177) ? 1 : 2;
  return v + __shfl_xor(v, x);
#endif
}

// quad broadcast of lane LANE (0..3) via DPP quad_perm[L,L,L,L].
template <int LANE>
__device__ __forceinline__ float qbcast(float v) {
#if __has_builtin(__builtin_amdgcn_mov_dpp)
  int m = __builtin_amdgcn_mov_dpp(__builtin_bit_cast(int, v), LANE * 0x55, 0xF, 0xF, true);
  return __builtin_bit_cast(float, m);
#else
  return __shfl(v, (threadIdx.x & 63 & ~3) + LANE);
#endif
}

__device__ __forceinline__ float bperm(float v, int byteidx) {
  return __builtin_bit_cast(float,
      __builtin_amdgcn_ds_bpermute(byteidx, __builtin_bit_cast(int, v)));
}
__device__ __forceinline__ float rfl(float v) {
  return __builtin_bit_cast(float,
      __builtin_amdgcn_readfirstlane(__builtin_bit_cast(int, v)));
}

// LDS-visibility-only barrier (vmcnt left free): imm 0xC07F.
__device__ __forceinline__ void lds_barrier() {
  __builtin_amdgcn_s_waitcnt(0xC07F);
  __builtin_amdgcn_s_barrier();
}

// ---------------------------------------------------------------------------
// gin GEMM: gin[(b*2+dir)*512+t][p] = bias[r] + x[b,t]·W_ih[r,:], with
// r = (p&3)*100 + (p>>2) so scan thread tid reads position tid directly.
// ---------------------------------------------------------------------------
__global__ __launch_bounds__(448, 2) void gin_gemm2(
    const int* __restrict__ tok, const float* __restrict__ emb,
    const float* __restrict__ w_ih_f, const float* __restrict__ b_ih_f,
    const float* __restrict__ b_hh_f,
    const float* __restrict__ w_ih_b, const float* __restrict__ b_ih_b,
    const float* __restrict__ b_hh_b,
    unsigned short* __restrict__ gin16)
{
  const int tid  = threadIdx.x;
  const int tile = blockIdx.x & 511;
  const int dir  = blockIdx.x >> 9;
  const size_t m0 = (size_t)tile * 128;
  const int b  = (int)(m0 >> 9);
  const int t0 = (int)(m0 & 511);

  const float* w_ih = dir ? w_ih_b : w_ih_f;
  const float* b_ih = dir ? b_ih_b : b_ih_f;
  const float* b_hh = dir ? b_hh_b : b_hh_f;

  __shared__ __align__(16) unsigned int xs[128 * 52];

  for (int i = tid; i < 128 * 32; i += 448) {
    int r = i >> 5, q = i & 31;
    if (q < 25) {
      int tk = tok[m0 + r];
      float4 v = ((const float4*)(emb + (size_t)tk * DD))[q];
      xs[r * 52 + 2 * q]     = pk(v.x, v.y);
      xs[r * 52 + 2 * q + 1] = pk(v.z, v.w);
    }
  }

  const bool act = tid < NG;
  const int r0 = (tid & 3) * 100 + (tid >> 2);
  h2_t w0[50];
  float bias = 0.f;
  if (act) {
    const float4* wr = (const float4*)(w_ih + (size_t)r0 * DD);
#pragma unroll
    for (int kk = 0; kk < 25; ++kk) {
      float4 a = wr[kk];
      w0[2 * kk]     = __builtin_amdgcn_cvt_pkrtz(a.x, a.y);
      w0[2 * kk + 1] = __builtin_amdgcn_cvt_pkrtz(a.z, a.w);
    }
    bias = b_ih[r0] + b_hh[r0];
  }
  __syncthreads();

  if (act) {
    unsigned short* op = gin16 + ((size_t)(b * 2 + dir) * TT + t0) * NG + tid;
    for (int r = 0; r < 128; ++r) {
      const unsigned int* xr = xs + r * 52;
      float a0 = bias, a1 = 0.f, a2 = 0.f, a3 = 0.f;
#pragma unroll
      for (int g = 0; g < 12; ++g) {
        uint4 u = ((const uint4*)xr)[g];
        a0 = fdot2(w0[4 * g],     bc_h2(u.x), a0);
        a1 = fdot2(w0[4 * g + 1], bc_h2(u.y), a1);
        a2 = fdot2(w0[4 * g + 2], bc_h2(u.z), a2);
        a3 = fdot2(w0[4 * g + 3], bc_h2(u.w), a3);
      }
      a0 = fdot2(w0[48], bc_h2(xr[48]), a0);
      a1 = fdot2(w0[49], bc_h2(xr[49]), a1);
      *op = __builtin_bit_cast(unsigned short, (__fp16)((a0 + a1) + (a2 + a3)));
      op += NG;
    }
  }
}

// ---------------------------------------------------------------------------
// LSTM scan v5: one block per (batch, direction), 512 threads = 8 waves.
// Unit lanes (tid<400): (unit j = tid>>2, K-slice s = tid&3). Per step:
//   gin prefetch via pointer increment (clamped), 4 gates x 14 fdot2 on own
//   h-slice, 8 DPP quad-adds -> all-gate sums, lane s activates ONLY gate s
//   (2 trans), 4 DPP quad-broadcasts distribute i,f,g,o (bitwise identical),
//   redundant c update, lane 0 writes h f16 to double-buffered LDS.
// Wave 7: 50 emission lanes compute em[t-1] = w_tag·h(t-1), f32 stores.
// ---------------------------------------------------------------------------
__global__ __launch_bounds__(512, 2) void lstm_scan5(
    const unsigned short* __restrict__ gin16,
    const float* __restrict__ w_hh_f, const float* __restrict__ w_hh_b,
    const float* __restrict__ w_tag, const float* __restrict__ b_tag,
    float* __restrict__ em_f, float* __restrict__ em_b)
{
  const int tid = threadIdx.x;
  const int b   = blockIdx.x & 127;
  const int dir = blockIdx.x >> 7;
  const float* w_hh = dir ? w_hh_b : w_hh_f;

  __shared__ __align__(16) unsigned int hls[2][52];

  const bool uact = tid < NG;
  const int j = tid >> 2;
  const int s = tid & 3;
  const int od = 12 * s;
  const int nn = (s == 3) ? 14 : 12;

  h2_t wA[14], wB[14], wC[14], wD[14];
  if (uact) {
#pragma unroll
    for (int d = 0; d < 14; ++d) {
      int dd = (d < nn) ? (od + d) : 0;
      const float* r0 = w_hh + (size_t)(0 * 100 + j) * HH + 2 * dd;
      const float* r1 = w_hh + (size_t)(1 * 100 + j) * HH + 2 * dd;
      const float* r2 = w_hh + (size_t)(2 * 100 + j) * HH + 2 * dd;
      const float* r3 = w_hh + (size_t)(3 * 100 + j) * HH + 2 * dd;
      h2_t z = __builtin_amdgcn_cvt_pkrtz(0.f, 0.f);
      wA[d] = (d < nn) ? __builtin_amdgcn_cvt_pkrtz(r0[0], r0[1]) : z;
      wB[d] = (d < nn) ? __builtin_amdgcn_cvt_pkrtz(r1[0], r1[1]) : z;
      wC[d] = (d < nn) ? __builtin_amdgcn_cvt_pkrtz(r2[0], r2[1]) : z;
      wD[d] = (d < nn) ? __builtin_amdgcn_cvt_pkrtz(r3[0], r3[1]) : z;
    }
  }
  // activation constants: sigmoid for s=0,1,3; tanh for s=2
  const float kk2 = (s == 2) ? (2.f * F_LOG2E) : (-F_LOG2E);
  const float cA  = (s == 2) ? -2.f : 1.f;
  const float cB  = (s == 2) ? 1.f : 0.f;

  // emission lanes
  const int el = tid - 448;
  const bool eact = (el >= 0) && (el < 50);
  const int l  = (el >= 0) ? (el >> 1) : 0;
  const int hf = (el >= 0) ? (el & 1) : 0;
  const int eo = hf ? 24 : 0;
  const int en = hf ? 26 : 24;
  h2_t wt[26];
  float bt = 0.f;
  if (eact) {
    const float* wr = w_tag + (size_t)l * 200 + dir * 100;
#pragma unroll
    for (int d = 0; d < 26; ++d) {
      int dd = (d < en) ? (eo + d) : 0;
      h2_t z = __builtin_amdgcn_cvt_pkrtz(0.f, 0.f);
      wt[d] = (d < en) ? __builtin_amdgcn_cvt_pkrtz(wr[2 * dd], wr[2 * dd + 1]) : z;
    }
    if (dir == 0 && hf == 0) bt = b_tag[l];
  }
  float* emo = dir ? em_b : em_f;

  if (tid < 52) { hls[0][tid] = 0u; hls[1][tid] = 0u; }

  const unsigned short* gb = gin16 + (size_t)(b * 2 + dir) * TT * NG + tid;
  const ptrdiff_t stp = dir ? -(ptrdiff_t)NG : (ptrdiff_t)NG;
  const unsigned short* lastp = gb + (size_t)(dir ? 0 : (TT - 1)) * NG;
  const unsigned short* pf = gb + (size_t)(dir ? (TT - 3) : 2) * NG;

  float c = 0.f;
  unsigned short g0 = 0, g1 = 0;
  if (uact) {
    g0 = gb[(size_t)(dir ? (TT - 1) : 0) * NG];
    g1 = gb[(size_t)(dir ? (TT - 2) : 1) * NG];
  }
  __syncthreads();

  for (int t = 0; t < TT; ++t) {
    if (uact) {
      const unsigned short* q = (t < TT - 2) ? pf : lastp;
      unsigned short g2 = *q;
      pf += stp;

      const unsigned int* hp = hls[t & 1] + od;
      uint4 u0 = *((const uint4*)hp);
      uint4 u1 = *((const uint4*)(hp + 4));
      uint4 u2 = *((const uint4*)(hp + 8));
      uint2 u3 = *((const uint2*)(hp + 12));

      float p0, p1, p2, p3;
      p0 = fdot2(wA[0], bc_h2(u0.x), 0.f);
      p1 = fdot2(wB[0], bc_h2(u0.x), 0.f);
      p2 = fdot2(wC[0], bc_h2(u0.x), 0.f);
      p3 = fdot2(wD[0], bc_h2(u0.x), 0.f);
#define STEP_D(d, hh) \
      p0 = fdot2(wA[d], bc_h2(hh), p0); p1 = fdot2(wB[d], bc_h2(hh), p1); \
      p2 = fdot2(wC[d], bc_h2(hh), p2); p3 = fdot2(wD[d], bc_h2(hh), p3);
      STEP_D(1, u0.y)  STEP_D(2, u0.z)  STEP_D(3, u0.w)
      STEP_D(4, u1.x)  STEP_D(5, u1.y)  STEP_D(6, u1.z)  STEP_D(7, u1.w)
      STEP_D(8, u2.x)  STEP_D(9, u2.y)  STEP_D(10, u2.z) STEP_D(11, u2.w)
      STEP_D(12, u3.x) STEP_D(13, u3.y)
#undef STEP_D

      p0 = qadd<78>(qadd<177>(p0));
      p1 = qadd<78>(qadd<177>(p1));
      p2 = qadd<78>(qadd<177>(p2));
      p3 = qadd<78>(qadd<177>(p3));

      // own-gate activation only
      float psel = (s == 0) ? p0 : (s == 1) ? p1 : (s == 2) ? p2 : p3;
      float gate = psel + (float)__builtin_bit_cast(__fp16, g0);
      float y  = fexp2(kk2 * gate);
      float rr = frcp(1.f + y);
      float actv = fmaf(cA, rr, cB);

      float iv = qbcast<0>(actv);
      float fv = qbcast<1>(actv);
      float gv = qbcast<2>(actv);
      float ov = qbcast<3>(actv);
      c = fmaf(fv, c, iv * gv);
      float hvv = ov * tanh_f(c);
      if (s == 0) ((__fp16*)(hls[(t + 1) & 1]))[j] = (__fp16)hvv;
      g0 = g1; g1 = g2;
    } else if (eact && t > 0) {
      const unsigned int* hp = hls[t & 1] + eo;
      uint4 e0 = *((const uint4*)hp);
      uint4 e1 = *((const uint4*)(hp + 4));
      uint4 e2 = *((const uint4*)(hp + 8));
      uint4 e3 = *((const uint4*)(hp + 12));
      uint4 e4 = *((const uint4*)(hp + 16));
      uint4 e5 = *((const uint4*)(hp + 20));
      uint2 e6 = *((const uint2*)(hp + 24));
      float a0 = 0.f, a1 = 0.f, a2 = 0.f, a3 = 0.f;
#define ESTEP(d, hh) { h2_t h = bc_h2(hh); \
      if ((d & 3) == 0) a0 = fdot2(wt[d], h, a0); \
      else if ((d & 3) == 1) a1 = fdot2(wt[d], h, a1); \
      else if ((d & 3) == 2) a2 = fdot2(wt[d], h, a2); \
      else a3 = fdot2(wt[d], h, a3); }
      ESTEP(0, e0.x) ESTEP(1, e0.y) ESTEP(2, e0.z) ESTEP(3, e0.w)
      ESTEP(4, e1.x) ESTEP(5, e1.y) ESTEP(6, e1.z) ESTEP(7, e1.w)
      ESTEP(8, e2.x) ESTEP(9, e2.y) ESTEP(10, e2.z) ESTEP(11, e2.w)
      ESTEP(12, e3.x) ESTEP(13, e3.y) ESTEP(14, e3.z) ESTEP(15, e3.w)
      ESTEP(16, e4.x) ESTEP(17, e4.y) ESTEP(18, e4.z) ESTEP(19, e4.w)
      ESTEP(20, e5.x) ESTEP(21, e5.y) ESTEP(22, e5.z) ESTEP(23, e5.w)
      ESTEP(24, e6.x) ESTEP(25, e6.y)
#undef ESTEP
      float ss = (a0 + a1) + (a2 + a3);
      float tot = qadd<177>(ss);
      if (hf == 0) {
        int tp = t - 1;
        int ttp = dir ? (TT - 1 - tp) : tp;
        emo[((size_t)b * TT + ttp) * LL + l] = tot + bt;
      }
    }
    lds_barrier();
  }

  // epilogue: emission for the last h (in hls[0] after 512 steps)
  if (eact) {
    const unsigned int* hp = hls[0] + eo;
    uint4 e0 = *((const uint4*)hp);
    uint4 e1 = *((const uint4*)(hp + 4));
    uint4 e2 = *((const uint4*)(hp + 8));
    uint4 e3 = *((const uint4*)(hp + 12));
    uint4 e4 = *((const uint4*)(hp + 16));
    uint4 e5 = *((const uint4*)(hp + 20));
    uint2 e6 = *((const uint2*)(hp + 24));
    unsigned int ev[26] = {e0.x, e0.y, e0.z, e0.w, e1.x, e1.y, e1.z, e1.w,
                           e2.x, e2.y, e2.z, e2.w, e3.x, e3.y, e3.z, e3.w,
                           e4.x, e4.y, e4.z, e4.w, e5.x, e5.y, e5.z, e5.w,
                           e6.x, e6.y};
    float a0 = 0.f, a1 = 0.f, a2 = 0.f, a3 = 0.f;
#pragma unroll
    for (int d = 0; d < 26; ++d) {
      h2_t h = bc_h2(ev[d]);
      if ((d & 3) == 0) a0 = fdot2(wt[d], h, a0);
      else if ((d & 3) == 1) a1 = fdot2(wt[d], h, a1);
      else if ((d & 3) == 2) a2 = fdot2(wt[d], h, a2);
      else a3 = fdot2(wt[d], h, a3);
    }
    float ss = (a0 + a1) + (a2 + a3);
    float tot = qadd<177>(ss);
    if (hf == 0) {
      int ttp = dir ? 0 : (TT - 1);
      emo[((size_t)b * TT + ttp) * LL + l] = tot + bt;
    }
  }
}

// ---------------------------------------------------------------------------
// FALLBACK scan (small ws): writes hc16 f16.
// ---------------------------------------------------------------------------
__global__ __launch_bounds__(512, 2) void lstm_scan_fb(
    const int* __restrict__ tok, const float* __restrict__ emb,
    const float* __restrict__ w_ih_f, const float* __restrict__ w_hh_f,
    const float* __restrict__ b_ih_f, const float* __restrict__ b_hh_f,
    const float* __restrict__ w_ih_b, const float* __restrict__ w_hh_b,
    const float* __restrict__ b_ih_b, const float* __restrict__ b_hh_b,
    unsigned short* __restrict__ hc16)
{
  const int tid = threadIdx.x;
  const int b   = blockIdx.x & 127;
  const int dir = blockIdx.x >> 7;

  const float* w_ih = dir ? w_ih_b : w_ih_f;
  const float* w_hh = dir ? w_hh_b : w_hh_f;
  const float* b_ih = dir ? b_ih_b : b_ih_f;
  const float* b_hh = dir ? b_hh_b : b_hh_f;

  __shared__ __align__(16) unsigned int xs[2][64];
  __shared__ __align__(16) unsigned int hls[64];
  __shared__ float gl[NG];

  h2_t wih[50], whh[50];
  float bias = 0.f;
  if (tid < NG) {
    const float4* wi = (const float4*)(w_ih + tid * DD);
    const float4* wh = (const float4*)(w_hh + tid * DD);
#pragma unroll
    for (int kk = 0; kk < 25; ++kk) {
      float4 a = wi[kk];
      wih[2 * kk]     = __builtin_amdgcn_cvt_pkrtz(a.x, a.y);
      wih[2 * kk + 1] = __builtin_amdgcn_cvt_pkrtz(a.z, a.w);
      float4 c = wh[kk];
      whh[2 * kk]     = __builtin_amdgcn_cvt_pkrtz(c.x, c.y);
      whh[2 * kk + 1] = __builtin_amdgcn_cvt_pkrtz(c.z, c.w);
    }
    bias = b_ih[tid] + b_hh[tid];
  }
  if (tid < 2) { xs[0][50 + tid] = 0u; xs[1][50 + tid] = 0u; hls[50 + tid] = 0u; }
  if (tid < 50) hls[tid] = 0u;

  const int base = b * TT;
  if (tid >= 448 && tid < 498) {
    int tt0 = dir ? (TT - 1) : 0;
    int i = tid - 448;
    int tk = tok[base + tt0];
    float2 v = ((const float2*)(emb + (size_t)tk * DD))[i];
    xs[0][i] = pk(v.x, v.y);
  }
  __syncthreads();

  float cst = 0.f;
  unsigned short* hcb = hc16 + (size_t)base * 200 + dir * 100;

  for (int t = 0; t < TT; ++t) {
    const int buf = t & 1;
    const int tt  = dir ? (TT - 1 - t) : t;

    if (tid < NG) {
      float a0 = bias, a1 = 0.f, a2 = 0.f, a3 = 0.f;
      const unsigned int* xp = xs[buf];
#pragma unroll
      for (int g = 0; g < 13; ++g) {
        uint4 u = ((const uint4*)xp)[g];
        const int k = 4 * g;
        a0 = fdot2(wih[k], bc_h2(u.x), a0);
        a1 = fdot2(wih[k + 1], bc_h2(u.y), a1);
        if (k + 2 < 50) a2 = fdot2(wih[k + 2], bc_h2(u.z), a2);
        if (k + 3 < 50) a3 = fdot2(wih[k + 3], bc_h2(u.w), a3);
      }
#pragma unroll
      for (int g = 0; g < 13; ++g) {
        uint4 u = ((const uint4*)hls)[g];
        const int k = 4 * g;
        a0 = fdot2(whh[k], bc_h2(u.x), a0);
        a1 = fdot2(whh[k + 1], bc_h2(u.y), a1);
        if (k + 2 < 50) a2 = fdot2(whh[k + 2], bc_h2(u.z), a2);
        if (k + 3 < 50) a3 = fdot2(whh[k + 3], bc_h2(u.w), a3);
      }
      float accs = (a0 + a1) + (a2 + a3);
      float av = (tid >= 200 && tid < 300) ? tanh_f(accs) : sigmoid_f(accs);
      gl[tid] = av;
    } else if (tid >= 448 && tid < 498 && t < TT - 1) {
      int ttn = dir ? (TT - 2 - t) : (t + 1);
      int i = tid - 448;
      int tk = tok[base + ttn];
      float2 v = ((const float2*)(emb + (size_t)tk * DD))[i];
      xs[buf ^ 1][i] = pk(v.x, v.y);
    }
    __syncthreads();

    if (tid < HH) {
      float gi = gl[tid], gf = gl[tid + 100], gg = gl[tid + 200], go = gl[tid + 300];
      cst = gf * cst + gi * gg;
      float hv = go * tanh_f(cst);
      __fp16 h16 = (__fp16)hv;
      ((__fp16*)hls)[tid] = h16;
      hcb[(size_t)tt * 200 + tid] = __builtin_bit_cast(unsigned short, h16);
    }
    __syncthreads();
  }
}

// Fallback emissions kernel.
__global__ __launch_bounds__(256, 2) void emis2(
    const unsigned short* __restrict__ hc16, const float* __restrict__ w_tag,
    const float* __restrict__ b_tag, float* __restrict__ em)
{
  __shared__ unsigned int hsh[64 * 101];
  __shared__ unsigned int wsh[25 * 100];
  const int tid = threadIdx.x;
  const size_t m0 = (size_t)blockIdx.x * 64;

  const unsigned int* hcu = (const unsigned int*)hc16;
  for (int i = tid; i < 64 * 100; i += 256) {
    int r = i / 100;
    int k = i - r * 100;
    hsh[r * 101 + k] = hcu[m0 * 100 + i];
  }
  for (int i = tid; i < 25 * 100; i += 256) {
    float2 wv = ((const float2*)w_tag)[i];
    wsh[i] = pk(wv.x, wv.y);
  }
  __syncthreads();

  const int r = tid & 63, q = tid >> 6;
  int lidx[7];
  bool lv[7];
  float acc[7];
#pragma unroll
  for (int ii = 0; ii < 7; ++ii) {
    int l = q + 4 * ii;
    lv[ii] = (l < LL);
    lidx[ii] = lv[ii] ? l : 0;
    acc[ii] = lv[ii] ? b_tag[lidx[ii]] : 0.f;
  }
  const unsigned int* hrow = hsh + r * 101;
#pragma unroll 2
  for (int k = 0; k < 100; ++k) {
    h2_t hv = bc_h2(hrow[k]);
#pragma unroll
    for (int ii = 0; ii < 7; ++ii)
      acc[ii] = fdot2(hv, bc_h2(wsh[lidx[ii] * 100 + k]), acc[ii]);
  }
#pragma unroll
  for (int ii = 0; ii < 7; ++ii)
    if (lv[ii]) em[(m0 + r) * LL + lidx[ii]] = acc[ii];
}

// ---------------------------------------------------------------------------
// CRF v4: standard-domain matvec scan. Per step: ONE exp2 per lane
// (A = 2^(a - sh)), 25 ds_bpermute broadcasts, 25 f32 FMA with precomputed
// E_ij = 2^(T_ij*log2e), one log2. Identical math to per-element lse.
// Wave 0 = partition (side 0 fwd t=0..255 / side 1 bwd 511..256);
// wave 1 (side-0 blocks) = gold path score.
// ---------------------------------------------------------------------------
__global__ __launch_bounds__(128) void crf_scan4(
    const float* __restrict__ em_f, const float* __restrict__ em_b,
    const int* __restrict__ tags, const int* __restrict__ lengths,
    const float* __restrict__ trans,
    const float* __restrict__ startt, const float* __restrict__ endt,
    float* __restrict__ ab, float* __restrict__ gold)
{
  const int tid  = threadIdx.x;
  const int b    = blockIdx.x >> 1;
  const int side = blockIdx.x & 1;

  if (tid < 64) {
    const int lane = tid;
    const int j = (lane < LL) ? lane : 0;
    const float* ef = em_f + (size_t)b * TT * LL;
    const float* eb = em_b + (size_t)b * TT * LL;

    float E[LL];
#pragma unroll
    for (int i = 0; i < LL; ++i) {
      float tv = (side == 0 ? trans[i * LL + j] : trans[j * LL + i]);
      E[i] = fexp2(tv * F_LOG2E);
    }

    float a, C = 0.f;
    if (side == 0) {
      a = (startt[j] + ef[j] + eb[j]) * F_LOG2E;
      float efn = ef[LL + j], ebn = eb[LL + j];
      for (int t = 1; t < 256; ++t) {
        float em2 = (efn + ebn) * F_LOG2E;
        int tn = (t + 1 < 256) ? t + 1 : t;
        efn = ef[(size_t)tn * LL + j];
        ebn = eb[(size_t)tn * LL + j];
        float sh = rfl(a);
        C += sh;
        float A = fexp2(a - sh);
        float s0 = 0.f, s1 = 0.f, s2 = 0.f, s3 = 0.f;
#pragma unroll
        for (int i = 0; i < LL; ++i) {
          float Ai = bperm(A, 4 * i);
          if ((i & 3) == 0) s0 = fmaf(Ai, E[i], s0);
          else if ((i & 3) == 1) s1 = fmaf(Ai, E[i], s1);
          else if ((i & 3) == 2) s2 = fmaf(Ai, E[i], s2);
          else s3 = fmaf(Ai, E[i], s3);
        }
        a = flog2((s0 + s1) + (s2 + s3)) + em2;
      }
    } else {
      a = endt[j] * F_LOG2E;
      float efn = ef[(size_t)(TT - 1) * LL + j], ebn = eb[(size_t)(TT - 1) * LL + j];
      for (int stpi = 0; stpi < 256; ++stpi) {
        int t1 = TT - 1 - stpi;
        float em2 = (efn + ebn) * F_LOG2E;
        int t1n = (stpi + 1 < 256) ? (t1 - 1) : t1;
        efn = ef[(size_t)t1n * LL + j];
        ebn = eb[(size_t)t1n * LL + j];
        float v = a + em2;
        float sh = rfl(v);
        C += sh;
        float A = fexp2(v - sh);
        float s0 = 0.f, s1 = 0.f, s2 = 0.f, s3 = 0.f;
#pragma unroll
        for (int i = 0; i < LL; ++i) {
          float Ai = bperm(A, 4 * i);
          if ((i & 3) == 0) s0 = fmaf(Ai, E[i], s0);
          else if ((i & 3) == 1) s1 = fmaf(Ai, E[i], s1);
          else if ((i & 3) == 2) s2 = fmaf(Ai, E[i], s2);
          else s3 = fmaf(Ai, E[i], s3);
        }
        a = flog2((s0 + s1) + (s2 + s3));
      }
    }
    if (lane < LL)
      ab[((size_t)b * 2 + side) * LL + lane] = (a + C) * F_LN2;
  } else if (side == 0) {
    const int lane = tid - 64;
    const int len = lengths[b];
    float acc = 0.f;
#pragma unroll
    for (int k = 0; k < 8; ++k) {
      int t = k * 64 + lane;
      int tg = tags[b * TT + t];
      size_t ei = ((size_t)b * TT + t) * LL + tg;
      float e = em_f[ei] + em_b[ei];
      float term;
      if (t == 0) term = startt[tg] + e;
      else        term = trans[tags[b * TT + t - 1] * LL + tg] + e;
      if (t == len - 1) term += endt[tg];
      if (t < len) acc += term;
    }
    for (int o = 32; o > 0; o >>= 1) acc += __shfl_down(acc, o);
    if (lane == 0) gold[b] = acc;
  }
}

// ---------------------------------------------------------------------------
// Final: logZ_b = lse(alpha+beta), out = sum_b (logZ_b - gold_b)
// ---------------------------------------------------------------------------
__global__ __launch_bounds__(128, 4) void crf_final(
    const float* __restrict__ ab, const float* __restrict__ gold,
    float* __restrict__ out)
{
  const int b = threadIdx.x;
  float v[LL];
  float m = -1e30f;
#pragma unroll
  for (int l = 0; l < LL; ++l) {
    v[l] = ab[((size_t)b * 2) * LL + l] + ab[((size_t)b * 2 + 1) * LL + l];
    m = fmaxf(m, v[l]);
  }
  float sacc = 0.f;
#pragma unroll
  for (int l = 0; l < LL; ++l) sacc += fexp2((v[l] - m) * F_LOG2E);
  float nll = (m + flog2(sacc) * F_LN2) - gold[b];

  for (int o = 32; o > 0; o >>= 1) nll += __shfl_down(nll, o);
  __shared__ float r2[2];
  if ((b & 63) == 0) r2[b >> 6] = nll;
  __syncthreads();
  if (b == 0) out[0] = r2[0] + r2[1];
}

extern "C" void kernel_launch(void* const* d_in, const int* in_sizes, int n_in,
                              void* d_out, int out_size, void* d_ws, size_t ws_size,
                              hipStream_t stream) {
  const int*   tok   = (const int*)d_in[0];
  const int*   tags  = (const int*)d_in[1];
  const int*   lens  = (const int*)d_in[2];
  const float* emb   = (const float*)d_in[3];
  const float* wif   = (const float*)d_in[4];
  const float* whf   = (const float*)d_in[5];
  const float* bif   = (const float*)d_in[6];
  const float* bhf   = (const float*)d_in[7];
  const float* wib   = (const float*)d_in[8];
  const float* whb   = (const float*)d_in[9];
  const float* bib   = (const float*)d_in[10];
  const float* bhb   = (const float*)d_in[11];
  const float* wtag  = (const float*)d_in[12];
  const float* btag  = (const float*)d_in[13];
  const float* trans = (const float*)d_in[14];
  const float* st    = (const float*)d_in[15];
  const float* en    = (const float*)d_in[16];

  char* wsb = (char*)d_ws;
  float* em_f = (float*)wsb;                                   //  6,553,600 B
  float* em_b = (float*)(wsb + 6553600);                       //  6,553,600 B
  float* gold = (float*)(wsb + 13107200);                      //        512 B
  float* ab   = (float*)(wsb + 13107712);                      //     25,600 B
  unsigned short* gin16 = (unsigned short*)(wsb + 13133312);   // 104,857,600 B
  const size_t need = 117990912ULL;

  if (ws_size >= need) {
    gin_gemm2<<<1024, 448, 0, stream>>>(tok, emb, wif, bif, bhf, wib, bib, bhb, gin16);
    lstm_scan5<<<256, 512, 0, stream>>>(gin16, whf, whb, wtag, btag, em_f, em_b);
  } else {
    unsigned short* hc16 = (unsigned short*)(wsb + 13133312);
    hipMemsetAsync(em_b, 0, 6553600, stream);
    lstm_scan_fb<<<256, 512, 0, stream>>>(tok, emb, wif, whf, bif, bhf,
                                          wib, whb, bib, bhb, hc16);
    emis2<<<1024, 256, 0, stream>>>(hc16, wtag, btag, em_f);
  }
  crf_scan4<<<256, 128, 0, stream>>>(em_f, em_b, tags, lens, trans, st, en, ab, gold);
  crf_final<<<1, 128, 0, stream>>>(ab, gold, (float*)d_out);
}

// Round 6
// 518.134 us; speedup vs baseline: 1.2983x; 1.1111x over previous
//
#include <hip/hip_runtime.h>
#include <cstdint>
#include <cstddef>

#define BB 128
#define TT 512
#define DD 100
#define HH 100
#define NG 400   // 4*H
#define LL 25
#define F_LOG2E 1.44269504088896340736f
#define F_LN2   0.69314718055994530942f

typedef __decltype(__builtin_amdgcn_cvt_pkrtz(0.f, 0.f)) h2_t;
typedef _Float16 v8h __attribute__((ext_vector_type(8)));
typedef float v4f __attribute__((ext_vector_type(4)));

__device__ __forceinline__ h2_t bc_h2(unsigned int u) {
  return __builtin_bit_cast(h2_t, u);
}
__device__ __forceinline__ unsigned int pk(float x, float y) {
  return __builtin_bit_cast(unsigned int, __builtin_amdgcn_cvt_pkrtz(x, y));
}

__device__ __forceinline__ float fdot2(h2_t a, h2_t b, float c) {
#if __has_builtin(__builtin_amdgcn_fdot2)
  return __builtin_amdgcn_fdot2(a, b, c, false);
#else
  return c + (float)a[0] * (float)b[0] + (float)a[1] * (float)b[1];
#endif
}

__device__ __forceinline__ float fexp2(float x) { return __builtin_amdgcn_exp2f(x); }
__device__ __forceinline__ float flog2(float x) { return __builtin_amdgcn_logf(x); }
__device__ __forceinline__ float frcp(float x)  { return __builtin_amdgcn_rcpf(x); }

__device__ __forceinline__ float sigmoid_f(float x) {
  return frcp(1.f + fexp2(-F_LOG2E * x));
}
__device__ __forceinline__ float tanh_f(float x) {
  float e = fexp2(2.f * F_LOG2E * x);
  return 1.f - 2.f * frcp(e + 1.f);
}

// quad all-reduce add via DPP. xor1 = quad_perm[1,0,3,2] = 177; xor2 = 78.
template <int CTRL>
__device__ __forceinline__ float qadd(float v) {
#if __has_builtin(__builtin_amdgcn_mov_dpp)
  int m = __builtin_amdgcn_mov_dpp(__builtin_bit_cast(int, v), CTRL, 0xF, 0xF, true);
  return v + __builtin_bit_cast(float, m);
#else
  int x = (CTRL == 177) ? 1 : 2;
  return v + __shfl_xor(v, x);
#endif
}

// quad broadcast of lane LANE (0..3) via DPP quad_perm[L,L,L,L].
template <int LANE>
__device__ __forceinline__ float qbcast(float v) {
#if __has_builtin(__builtin_amdgcn_mov_dpp)
  int m = __builtin_amdgcn_mov_dpp(__builtin_bit_cast(int, v), LANE * 0x55, 0xF, 0xF, true);
  return __builtin_bit_cast(float, m);
#else
  return __shfl(v, (threadIdx.x & 63 & ~3) + LANE);
#endif
}

__device__ __forceinline__ float bperm(float v, int byteidx) {
  return __builtin_bit_cast(float,
      __builtin_amdgcn_ds_bpermute(byteidx, __builtin_bit_cast(int, v)));
}
__device__ __forceinline__ float rfl(float v) {
  return __builtin_bit_cast(float,
      __builtin_amdgcn_readfirstlane(__builtin_bit_cast(int, v)));
}

// LDS-visibility-only barrier (vmcnt left free): imm 0xC07F.
__device__ __forceinline__ void lds_barrier() {
  __builtin_amdgcn_s_waitcnt(0xC07F);
  __builtin_amdgcn_s_barrier();
}

// ---------------------------------------------------------------------------
// gin via MFMA: gin[(b*2+dir)*512+t][p] = bias[r(p)] + x[b,t]·W_ih[r(p),:]
// with r(p) = (p&3)*100 + (p>>2). One block = 256 rows (same b) x one dir.
// W staged f16 in LDS, K zero-padded to 128 (row stride 68 dwords -> <=2-way
// bank aliasing, 16B aligned). A-frags loaded directly from emb (f32->f16).
// The K=96..127 frag needs no masking: B rows are zero there.
// mfma_f32_16x16x32_f16: A[m=lane&15][k=quad*8+j]; B[k][n=lane&15] same k map;
// C/D col=lane&15, row=quad*4+reg.
// ---------------------------------------------------------------------------
__global__ __launch_bounds__(256, 1) void gin_mfma(
    const int* __restrict__ tok, const float* __restrict__ emb,
    const float* __restrict__ w_ih_f, const float* __restrict__ b_ih_f,
    const float* __restrict__ b_hh_f,
    const float* __restrict__ w_ih_b, const float* __restrict__ b_ih_b,
    const float* __restrict__ b_hh_b,
    unsigned short* __restrict__ gin16)
{
  const int tid = threadIdx.x;
  const int dir = blockIdx.x & 1;
  const int rb  = blockIdx.x >> 1;        // 0..255
  const int b   = rb >> 1;
  const int t0  = (rb & 1) * 256;

  const float* w_ih = dir ? w_ih_b : w_ih_f;
  const float* b_ih = dir ? b_ih_b : b_ih_f;
  const float* b_hh = dir ? b_hh_b : b_hh_f;

  __shared__ __align__(16) unsigned int wlds[400 * 68];
  __shared__ float bias_l[400];

  for (int i = tid; i < 400 * 68; i += 256) {
    int p = i / 68;
    int d = i - p * 68;
    int r = (p & 3) * 100 + (p >> 2);
    unsigned int v = 0u;
    if (d < 50) {
      const float* wr = w_ih + (size_t)r * DD + 2 * d;
      v = pk(wr[0], wr[1]);
    }
    wlds[i] = v;
  }
  for (int i = tid; i < 400; i += 256) {
    int r = (i & 3) * 100 + (i >> 2);
    bias_l[i] = b_ih[r] + b_hh[r];
  }

  const int wv   = tid >> 6;
  const int lane = tid & 63;
  const int l16  = lane & 15;
  const int quad = lane >> 4;

  // A fragments: 4 rowgroups x 4 K-frags, straight from emb
  v8h af[4][4];
#pragma unroll
  for (int rg = 0; rg < 4; ++rg) {
    int mrow = wv * 64 + rg * 16 + l16;
    int tk = tok[b * TT + t0 + mrow];
    const float* xr = emb + (size_t)tk * DD;
    const int kb = quad * 8;
#pragma unroll
    for (int f = 0; f < 4; ++f) {
      uint4 u;
      if (f < 3) {
        const float* xp = xr + f * 32 + kb;
        float4 va = *(const float4*)(xp);
        float4 vb = *(const float4*)(xp + 4);
        u.x = pk(va.x, va.y); u.y = pk(va.z, va.w);
        u.z = pk(vb.x, vb.y); u.w = pk(vb.z, vb.w);
      } else {
        // k = 96 + quad*8 + j; only k<100 matters (B zero-padded beyond)
        float4 va = *(const float4*)(xr + 96);
        u.x = pk(va.x, va.y); u.y = pk(va.z, va.w);
        u.z = 0u; u.w = 0u;
      }
      af[rg][f] = __builtin_bit_cast(v8h, u);
    }
  }
  __syncthreads();

  const size_t chbase = ((size_t)(b * 2 + dir) * TT + t0) * NG;
  for (int c = 0; c < 25; ++c) {
    v8h bf[4];
    const unsigned int* wp = wlds + (16 * c + l16) * 68 + quad * 4;
#pragma unroll
    for (int f = 0; f < 4; ++f)
      bf[f] = __builtin_bit_cast(v8h, *(const uint4*)(wp + f * 16));
    float bias_v = bias_l[16 * c + l16];
#pragma unroll
    for (int rg = 0; rg < 4; ++rg) {
      v4f acc = {0.f, 0.f, 0.f, 0.f};
#pragma unroll
      for (int f = 0; f < 4; ++f)
        acc = __builtin_amdgcn_mfma_f32_16x16x32_f16(af[rg][f], bf[f], acc, 0, 0, 0);
      unsigned short* op = gin16 + chbase
          + (size_t)(wv * 64 + rg * 16 + quad * 4) * NG + 16 * c + l16;
#pragma unroll
      for (int r = 0; r < 4; ++r) {
        op[0] = __builtin_bit_cast(unsigned short, (__fp16)(acc[r] + bias_v));
        op += NG;
      }
    }
  }
}

// ---------------------------------------------------------------------------
// LSTM scan v6: one block per (batch, direction), 512 threads = 8 waves.
// Unit lanes: (unit j = tid>>2, K-slice s = tid&3); DPP quad reduce/bcast;
// gin prefetch via unconditional pointer walk (OOB lands in adjacent chain's
// rows of gin16 -> in-bounds, values unused). Time loop unrolled 2x (explicit
// LDS double-buffer). Wave 7 = 50 emission lanes (pointer-incremented store).
// ---------------------------------------------------------------------------
__global__ __launch_bounds__(512, 2) void lstm_scan6(
    const unsigned short* __restrict__ gin16,
    const float* __restrict__ w_hh_f, const float* __restrict__ w_hh_b,
    const float* __restrict__ w_tag, const float* __restrict__ b_tag,
    float* __restrict__ em_f, float* __restrict__ em_b)
{
  const int tid = threadIdx.x;
  const int b   = blockIdx.x & 127;
  const int dir = blockIdx.x >> 7;
  const float* w_hh = dir ? w_hh_b : w_hh_f;

  __shared__ __align__(16) unsigned int hls0[52];
  __shared__ __align__(16) unsigned int hls1[52];

  const bool uact = tid < NG;
  const int j = tid >> 2;
  const int s = tid & 3;
  const int od = 12 * s;
  const int nn = (s == 3) ? 14 : 12;

  h2_t wA[14], wB[14], wC[14], wD[14];
  if (uact) {
#pragma unroll
    for (int d = 0; d < 14; ++d) {
      int dd = (d < nn) ? (od + d) : 0;
      const float* r0 = w_hh + (size_t)(0 * 100 + j) * HH + 2 * dd;
      const float* r1 = w_hh + (size_t)(1 * 100 + j) * HH + 2 * dd;
      const float* r2 = w_hh + (size_t)(2 * 100 + j) * HH + 2 * dd;
      const float* r3 = w_hh + (size_t)(3 * 100 + j) * HH + 2 * dd;
      h2_t z = __builtin_amdgcn_cvt_pkrtz(0.f, 0.f);
      wA[d] = (d < nn) ? __builtin_amdgcn_cvt_pkrtz(r0[0], r0[1]) : z;
      wB[d] = (d < nn) ? __builtin_amdgcn_cvt_pkrtz(r1[0], r1[1]) : z;
      wC[d] = (d < nn) ? __builtin_amdgcn_cvt_pkrtz(r2[0], r2[1]) : z;
      wD[d] = (d < nn) ? __builtin_amdgcn_cvt_pkrtz(r3[0], r3[1]) : z;
    }
  }
  const float kk2 = (s == 2) ? (2.f * F_LOG2E) : (-F_LOG2E);
  const float cA  = (s == 2) ? -2.f : 1.f;
  const float cB  = (s == 2) ? 1.f : 0.f;

  const int el = tid - 448;
  const bool eact = (el >= 0) && (el < 50);
  const int l  = (el >= 0) ? (el >> 1) : 0;
  const int hf = (el >= 0) ? (el & 1) : 0;
  const int eo = hf ? 24 : 0;
  const int en = hf ? 26 : 24;
  h2_t wt[26];
  float bt = 0.f;
  if (eact) {
    const float* wr = w_tag + (size_t)l * 200 + dir * 100;
#pragma unroll
    for (int d = 0; d < 26; ++d) {
      int dd = (d < en) ? (eo + d) : 0;
      h2_t z = __builtin_amdgcn_cvt_pkrtz(0.f, 0.f);
      wt[d] = (d < en) ? __builtin_amdgcn_cvt_pkrtz(wr[2 * dd], wr[2 * dd + 1]) : z;
    }
    if (dir == 0 && hf == 0) bt = b_tag[l];
  }
  float* emo = dir ? em_b : em_f;
  float* emp = emo + ((size_t)b * TT + (dir ? (TT - 1) : 0)) * LL + l;
  const ptrdiff_t estep = dir ? -(ptrdiff_t)LL : (ptrdiff_t)LL;

  if (tid < 52) { hls0[tid] = 0u; hls1[tid] = 0u; }

  const unsigned short* gb = gin16 + (size_t)(b * 2 + dir) * TT * NG + tid;
  const ptrdiff_t stp = dir ? -(ptrdiff_t)NG : (ptrdiff_t)NG;
  const unsigned short* pf = gb + (size_t)(dir ? (TT - 3) : 2) * NG;

  float c = 0.f;
  unsigned short g0 = 0, g1 = 0;
  if (uact) {
    g0 = gb[(size_t)(dir ? (TT - 1) : 0) * NG];
    g1 = gb[(size_t)(dir ? (TT - 2) : 1) * NG];
  }
  __syncthreads();

#define SCAN_STEP(HRD, HWR, TVNZ)                                          \
  {                                                                        \
    if (uact) {                                                            \
      unsigned short g2 = *pf; pf += stp;                                  \
      const unsigned int* hp = (HRD) + od;                                 \
      uint4 u0 = *((const uint4*)hp);                                      \
      uint4 u1 = *((const uint4*)(hp + 4));                                \
      uint4 u2 = *((const uint4*)(hp + 8));                                \
      uint2 u3 = *((const uint2*)(hp + 12));                               \
      float p0, p1, p2, p3;                                                \
      p0 = fdot2(wA[0], bc_h2(u0.x), 0.f);                                 \
      p1 = fdot2(wB[0], bc_h2(u0.x), 0.f);                                 \
      p2 = fdot2(wC[0], bc_h2(u0.x), 0.f);                                 \
      p3 = fdot2(wD[0], bc_h2(u0.x), 0.f);                                 \
      SDOT(1, u0.y)  SDOT(2, u0.z)  SDOT(3, u0.w)                          \
      SDOT(4, u1.x)  SDOT(5, u1.y)  SDOT(6, u1.z)  SDOT(7, u1.w)           \
      SDOT(8, u2.x)  SDOT(9, u2.y)  SDOT(10, u2.z) SDOT(11, u2.w)          \
      SDOT(12, u3.x) SDOT(13, u3.y)                                        \
      p0 = qadd<78>(qadd<177>(p0));                                        \
      p1 = qadd<78>(qadd<177>(p1));                                        \
      p2 = qadd<78>(qadd<177>(p2));                                        \
      p3 = qadd<78>(qadd<177>(p3));                                        \
      float psel = (s == 0) ? p0 : (s == 1) ? p1 : (s == 2) ? p2 : p3;     \
      float gate = psel + (float)__builtin_bit_cast(__fp16, g0);           \
      float y  = fexp2(kk2 * gate);                                        \
      float rr = frcp(1.f + y);                                            \
      float actv = fmaf(cA, rr, cB);                                       \
      float iv = qbcast<0>(actv);                                          \
      float fv = qbcast<1>(actv);                                          \
      float gv = qbcast<2>(actv);                                          \
      float ov = qbcast<3>(actv);                                          \
      c = fmaf(fv, c, iv * gv);                                            \
      float hvv = ov * tanh_f(c);                                          \
      if (s == 0) ((__fp16*)(HWR))[j] = (__fp16)hvv;                       \
      g0 = g1; g1 = g2;                                                    \
    } else if (eact && (TVNZ)) {                                           \
      const unsigned int* hp = (HRD) + eo;                                 \
      uint4 e0 = *((const uint4*)hp);                                      \
      uint4 e1 = *((const uint4*)(hp + 4));                                \
      uint4 e2 = *((const uint4*)(hp + 8));                                \
      uint4 e3 = *((const uint4*)(hp + 12));                               \
      uint4 e4 = *((const uint4*)(hp + 16));                               \
      uint4 e5 = *((const uint4*)(hp + 20));                               \
      uint2 e6 = *((const uint2*)(hp + 24));                               \
      float a0, a1, a2, a3;                                                \
      a0 = fdot2(wt[0], bc_h2(e0.x), 0.f);                                 \
      a1 = fdot2(wt[1], bc_h2(e0.y), 0.f);                                 \
      a2 = fdot2(wt[2], bc_h2(e0.z), 0.f);                                 \
      a3 = fdot2(wt[3], bc_h2(e0.w), 0.f);                                 \
      EDOT(4, e1.x)  EDOT(5, e1.y)  EDOT(6, e1.z)  EDOT(7, e1.w)           \
      EDOT(8, e2.x)  EDOT(9, e2.y)  EDOT(10, e2.z) EDOT(11, e2.w)          \
      EDOT(12, e3.x) EDOT(13, e3.y) EDOT(14, e3.z) EDOT(15, e3.w)          \
      EDOT(16, e4.x) EDOT(17, e4.y) EDOT(18, e4.z) EDOT(19, e4.w)          \
      EDOT(20, e5.x) EDOT(21, e5.y) EDOT(22, e5.z) EDOT(23, e5.w)          \
      EDOT(24, e6.x) EDOT(25, e6.y)                                        \
      float ss = (a0 + a1) + (a2 + a3);                                    \
      float tot = qadd<177>(ss);                                           \
      if (hf == 0) *emp = tot + bt;                                        \
      emp += estep;                                                        \
    }                                                                      \
    lds_barrier();                                                         \
  }
#define SDOT(d, hh) \
  p0 = fdot2(wA[d], bc_h2(hh), p0); p1 = fdot2(wB[d], bc_h2(hh), p1); \
  p2 = fdot2(wC[d], bc_h2(hh), p2); p3 = fdot2(wD[d], bc_h2(hh), p3);
#define EDOT(d, hh) { h2_t h = bc_h2(hh); \
  if ((d & 3) == 0) a0 = fdot2(wt[d], h, a0); \
  else if ((d & 3) == 1) a1 = fdot2(wt[d], h, a1); \
  else if ((d & 3) == 2) a2 = fdot2(wt[d], h, a2); \
  else a3 = fdot2(wt[d], h, a3); }

  // t = 0 (no emission), then pairs
  SCAN_STEP(hls0, hls1, false)
  SCAN_STEP(hls1, hls0, true)
  for (int t = 2; t < TT; t += 2) {
    SCAN_STEP(hls0, hls1, true)
    SCAN_STEP(hls1, hls0, true)
  }
#undef SCAN_STEP
#undef SDOT

  // epilogue: emission for the last h (in hls0 after 512 steps)
  if (eact) {
    const unsigned int* hp = hls0 + eo;
    uint4 e0 = *((const uint4*)hp);
    uint4 e1 = *((const uint4*)(hp + 4));
    uint4 e2 = *((const uint4*)(hp + 8));
    uint4 e3 = *((const uint4*)(hp + 12));
    uint4 e4 = *((const uint4*)(hp + 16));
    uint4 e5 = *((const uint4*)(hp + 20));
    uint2 e6 = *((const uint2*)(hp + 24));
    float a0, a1, a2, a3;
    a0 = fdot2(wt[0], bc_h2(e0.x), 0.f);
    a1 = fdot2(wt[1], bc_h2(e0.y), 0.f);
    a2 = fdot2(wt[2], bc_h2(e0.z), 0.f);
    a3 = fdot2(wt[3], bc_h2(e0.w), 0.f);
    EDOT(4, e1.x)  EDOT(5, e1.y)  EDOT(6, e1.z)  EDOT(7, e1.w)
    EDOT(8, e2.x)  EDOT(9, e2.y)  EDOT(10, e2.z) EDOT(11, e2.w)
    EDOT(12, e3.x) EDOT(13, e3.y) EDOT(14, e3.z) EDOT(15, e3.w)
    EDOT(16, e4.x) EDOT(17, e4.y) EDOT(18, e4.z) EDOT(19, e4.w)
    EDOT(20, e5.x) EDOT(21, e5.y) EDOT(22, e5.z) EDOT(23, e5.w)
    EDOT(24, e6.x) EDOT(25, e6.y)
    float ss = (a0 + a1) + (a2 + a3);
    float tot = qadd<177>(ss);
    if (hf == 0) {
      int ttp = dir ? 0 : (TT - 1);
      emo[((size_t)b * TT + ttp) * LL + l] = tot + bt;
    }
  }
#undef EDOT
}

// ---------------------------------------------------------------------------
// FALLBACK scan (small ws): writes hc16 f16.
// ---------------------------------------------------------------------------
__global__ __launch_bounds__(512, 2) void lstm_scan_fb(
    const int* __restrict__ tok, const float* __restrict__ emb,
    const float* __restrict__ w_ih_f, const float* __restrict__ w_hh_f,
    const float* __restrict__ b_ih_f, const float* __restrict__ b_hh_f,
    const float* __restrict__ w_ih_b, const float* __restrict__ w_hh_b,
    const float* __restrict__ b_ih_b, const float* __restrict__ b_hh_b,
    unsigned short* __restrict__ hc16)
{
  const int tid = threadIdx.x;
  const int b   = blockIdx.x & 127;
  const int dir = blockIdx.x >> 7;

  const float* w_ih = dir ? w_ih_b : w_ih_f;
  const float* w_hh = dir ? w_hh_b : w_hh_f;
  const float* b_ih = dir ? b_ih_b : b_ih_f;
  const float* b_hh = dir ? b_hh_b : b_hh_f;

  __shared__ __align__(16) unsigned int xs[2][64];
  __shared__ __align__(16) unsigned int hls[64];
  __shared__ float gl[NG];

  h2_t wih[50], whh[50];
  float bias = 0.f;
  if (tid < NG) {
    const float4* wi = (const float4*)(w_ih + tid * DD);
    const float4* wh = (const float4*)(w_hh + tid * DD);
#pragma unroll
    for (int kk = 0; kk < 25; ++kk) {
      float4 a = wi[kk];
      wih[2 * kk]     = __builtin_amdgcn_cvt_pkrtz(a.x, a.y);
      wih[2 * kk + 1] = __builtin_amdgcn_cvt_pkrtz(a.z, a.w);
      float4 c = wh[kk];
      whh[2 * kk]     = __builtin_amdgcn_cvt_pkrtz(c.x, c.y);
      whh[2 * kk + 1] = __builtin_amdgcn_cvt_pkrtz(c.z, c.w);
    }
    bias = b_ih[tid] + b_hh[tid];
  }
  if (tid < 2) { xs[0][50 + tid] = 0u; xs[1][50 + tid] = 0u; hls[50 + tid] = 0u; }
  if (tid < 50) hls[tid] = 0u;

  const int base = b * TT;
  if (tid >= 448 && tid < 498) {
    int tt0 = dir ? (TT - 1) : 0;
    int i = tid - 448;
    int tk = tok[base + tt0];
    float2 v = ((const float2*)(emb + (size_t)tk * DD))[i];
    xs[0][i] = pk(v.x, v.y);
  }
  __syncthreads();

  float cst = 0.f;
  unsigned short* hcb = hc16 + (size_t)base * 200 + dir * 100;

  for (int t = 0; t < TT; ++t) {
    const int buf = t & 1;
    const int tt  = dir ? (TT - 1 - t) : t;

    if (tid < NG) {
      float a0 = bias, a1 = 0.f, a2 = 0.f, a3 = 0.f;
      const unsigned int* xp = xs[buf];
#pragma unroll
      for (int g = 0; g < 13; ++g) {
        uint4 u = ((const uint4*)xp)[g];
        const int k = 4 * g;
        a0 = fdot2(wih[k], bc_h2(u.x), a0);
        a1 = fdot2(wih[k + 1], bc_h2(u.y), a1);
        if (k + 2 < 50) a2 = fdot2(wih[k + 2], bc_h2(u.z), a2);
        if (k + 3 < 50) a3 = fdot2(wih[k + 3], bc_h2(u.w), a3);
      }
#pragma unroll
      for (int g = 0; g < 13; ++g) {
        uint4 u = ((const uint4*)hls)[g];
        const int k = 4 * g;
        a0 = fdot2(whh[k], bc_h2(u.x), a0);
        a1 = fdot2(whh[k + 1], bc_h2(u.y), a1);
        if (k + 2 < 50) a2 = fdot2(whh[k + 2], bc_h2(u.z), a2);
        if (k + 3 < 50) a3 = fdot2(whh[k + 3], bc_h2(u.w), a3);
      }
      float accs = (a0 + a1) + (a2 + a3);
      float av = (tid >= 200 && tid < 300) ? tanh_f(accs) : sigmoid_f(accs);
      gl[tid] = av;
    } else if (tid >= 448 && tid < 498 && t < TT - 1) {
      int ttn = dir ? (TT - 2 - t) : (t + 1);
      int i = tid - 448;
      int tk = tok[base + ttn];
      float2 v = ((const float2*)(emb + (size_t)tk * DD))[i];
      xs[buf ^ 1][i] = pk(v.x, v.y);
    }
    __syncthreads();

    if (tid < HH) {
      float gi = gl[tid], gf = gl[tid + 100], gg = gl[tid + 200], go = gl[tid + 300];
      cst = gf * cst + gi * gg;
      float hv = go * tanh_f(cst);
      __fp16 h16 = (__fp16)hv;
      ((__fp16*)hls)[tid] = h16;
      hcb[(size_t)tt * 200 + tid] = __builtin_bit_cast(unsigned short, h16);
    }
    __syncthreads();
  }
}

// Fallback emissions kernel.
__global__ __launch_bounds__(256, 2) void emis2(
    const unsigned short* __restrict__ hc16, const float* __restrict__ w_tag,
    const float* __restrict__ b_tag, float* __restrict__ em)
{
  __shared__ unsigned int hsh[64 * 101];
  __shared__ unsigned int wsh[25 * 100];
  const int tid = threadIdx.x;
  const size_t m0 = (size_t)blockIdx.x * 64;

  const unsigned int* hcu = (const unsigned int*)hc16;
  for (int i = tid; i < 64 * 100; i += 256) {
    int r = i / 100;
    int k = i - r * 100;
    hsh[r * 101 + k] = hcu[m0 * 100 + i];
  }
  for (int i = tid; i < 25 * 100; i += 256) {
    float2 wv = ((const float2*)w_tag)[i];
    wsh[i] = pk(wv.x, wv.y);
  }
  __syncthreads();

  const int r = tid & 63, q = tid >> 6;
  int lidx[7];
  bool lv[7];
  float acc[7];
#pragma unroll
  for (int ii = 0; ii < 7; ++ii) {
    int l = q + 4 * ii;
    lv[ii] = (l < LL);
    lidx[ii] = lv[ii] ? l : 0;
    acc[ii] = lv[ii] ? b_tag[lidx[ii]] : 0.f;
  }
  const unsigned int* hrow = hsh + r * 101;
#pragma unroll 2
  for (int k = 0; k < 100; ++k) {
    h2_t hv = bc_h2(hrow[k]);
#pragma unroll
    for (int ii = 0; ii < 7; ++ii)
      acc[ii] = fdot2(hv, bc_h2(wsh[lidx[ii] * 100 + k]), acc[ii]);
  }
#pragma unroll
  for (int ii = 0; ii < 7; ++ii)
    if (lv[ii]) em[(m0 + r) * LL + lidx[ii]] = acc[ii];
}

// ---------------------------------------------------------------------------
// CRF v5: matvec scan with ONE exp per lane per step and depth-2 em prefetch.
// Wave 0 = partition (side 0 fwd t=0..255 / side 1 bwd 511..256);
// wave 1 (side-0 blocks) = gold path score.
// ---------------------------------------------------------------------------
__global__ __launch_bounds__(128) void crf_scan5(
    const float* __restrict__ em_f, const float* __restrict__ em_b,
    const int* __restrict__ tags, const int* __restrict__ lengths,
    const float* __restrict__ trans,
    const float* __restrict__ startt, const float* __restrict__ endt,
    float* __restrict__ ab, float* __restrict__ gold)
{
  const int tid  = threadIdx.x;
  const int b    = blockIdx.x >> 1;
  const int side = blockIdx.x & 1;

  if (tid < 64) {
    const int lane = tid;
    const int j = (lane < LL) ? lane : 0;
    const float* ef = em_f + (size_t)b * TT * LL;
    const float* eb = em_b + (size_t)b * TT * LL;

    float E[LL];
#pragma unroll
    for (int i = 0; i < LL; ++i) {
      float tv = (side == 0 ? trans[i * LL + j] : trans[j * LL + i]);
      E[i] = fexp2(tv * F_LOG2E);
    }

    float a, C = 0.f;
    if (side == 0) {
      a = (startt[j] + ef[j] + eb[j]) * F_LOG2E;
      float efA = ef[LL + j],     ebA = eb[LL + j];      // t=1
      float efB = ef[2 * LL + j], ebB = eb[2 * LL + j];  // t=2
      for (int t = 1; t < 256; ++t) {
        float em2 = (efA + ebA) * F_LOG2E;
        int tn = (t + 2 < 256) ? (t + 2) : 255;
        efA = efB; ebA = ebB;
        efB = ef[(size_t)tn * LL + j];
        ebB = eb[(size_t)tn * LL + j];
        float sh = rfl(a);
        C += sh;
        float A = fexp2(a - sh);
        float s0 = 0.f, s1 = 0.f, s2 = 0.f, s3 = 0.f;
#pragma unroll
        for (int i = 0; i < LL; ++i) {
          float Ai = bperm(A, 4 * i);
          if ((i & 3) == 0) s0 = fmaf(Ai, E[i], s0);
          else if ((i & 3) == 1) s1 = fmaf(Ai, E[i], s1);
          else if ((i & 3) == 2) s2 = fmaf(Ai, E[i], s2);
          else s3 = fmaf(Ai, E[i], s3);
        }
        a = flog2((s0 + s1) + (s2 + s3)) + em2;
      }
    } else {
      a = endt[j] * F_LOG2E;
      float efA = ef[(size_t)(TT - 1) * LL + j], ebA = eb[(size_t)(TT - 1) * LL + j];
      float efB = ef[(size_t)(TT - 2) * LL + j], ebB = eb[(size_t)(TT - 2) * LL + j];
      for (int stpi = 0; stpi < 256; ++stpi) {
        float em2 = (efA + ebA) * F_LOG2E;
        int t1n = (stpi + 2 < 256) ? (TT - 3 - stpi) : 256;
        efA = efB; ebA = ebB;
        efB = ef[(size_t)t1n * LL + j];
        ebB = eb[(size_t)t1n * LL + j];
        float v = a + em2;
        float sh = rfl(v);
        C += sh;
        float A = fexp2(v - sh);
        float s0 = 0.f, s1 = 0.f, s2 = 0.f, s3 = 0.f;
#pragma unroll
        for (int i = 0; i < LL; ++i) {
          float Ai = bperm(A, 4 * i);
          if ((i & 3) == 0) s0 = fmaf(Ai, E[i], s0);
          else if ((i & 3) == 1) s1 = fmaf(Ai, E[i], s1);
          else if ((i & 3) == 2) s2 = fmaf(Ai, E[i], s2);
          else s3 = fmaf(Ai, E[i], s3);
        }
        a = flog2((s0 + s1) + (s2 + s3));
      }
    }
    if (lane < LL)
      ab[((size_t)b * 2 + side) * LL + lane] = (a + C) * F_LN2;
  } else if (side == 0) {
    const int lane = tid - 64;
    const int len = lengths[b];
    float acc = 0.f;
#pragma unroll
    for (int k = 0; k < 8; ++k) {
      int t = k * 64 + lane;
      int tg = tags[b * TT + t];
      size_t ei = ((size_t)b * TT + t) * LL + tg;
      float e = em_f[ei] + em_b[ei];
      float term;
      if (t == 0) term = startt[tg] + e;
      else        term = trans[tags[b * TT + t - 1] * LL + tg] + e;
      if (t == len - 1) term += endt[tg];
      if (t < len) acc += term;
    }
    for (int o = 32; o > 0; o >>= 1) acc += __shfl_down(acc, o);
    if (lane == 0) gold[b] = acc;
  }
}

// ---------------------------------------------------------------------------
// Final: logZ_b = lse(alpha+beta), out = sum_b (logZ_b - gold_b)
// ---------------------------------------------------------------------------
__global__ __launch_bounds__(128, 4) void crf_final(
    const float* __restrict__ ab, const float* __restrict__ gold,
    float* __restrict__ out)
{
  const int b = threadIdx.x;
  float v[LL];
  float m = -1e30f;
#pragma unroll
  for (int l = 0; l < LL; ++l) {
    v[l] = ab[((size_t)b * 2) * LL + l] + ab[((size_t)b * 2 + 1) * LL + l];
    m = fmaxf(m, v[l]);
  }
  float sacc = 0.f;
#pragma unroll
  for (int l = 0; l < LL; ++l) sacc += fexp2((v[l] - m) * F_LOG2E);
  float nll = (m + flog2(sacc) * F_LN2) - gold[b];

  for (int o = 32; o > 0; o >>= 1) nll += __shfl_down(nll, o);
  __shared__ float r2[2];
  if ((b & 63) == 0) r2[b >> 6] = nll;
  __syncthreads();
  if (b == 0) out[0] = r2[0] + r2[1];
}

extern "C" void kernel_launch(void* const* d_in, const int* in_sizes, int n_in,
                              void* d_out, int out_size, void* d_ws, size_t ws_size,
                              hipStream_t stream) {
  const int*   tok   = (const int*)d_in[0];
  const int*   tags  = (const int*)d_in[1];
  const int*   lens  = (const int*)d_in[2];
  const float* emb   = (const float*)d_in[3];
  const float* wif   = (const float*)d_in[4];
  const float* whf   = (const float*)d_in[5];
  const float* bif   = (const float*)d_in[6];
  const float* bhf   = (const float*)d_in[7];
  const float* wib   = (const float*)d_in[8];
  const float* whb   = (const float*)d_in[9];
  const float* bib   = (const float*)d_in[10];
  const float* bhb   = (const float*)d_in[11];
  const float* wtag  = (const float*)d_in[12];
  const float* btag  = (const float*)d_in[13];
  const float* trans = (const float*)d_in[14];
  const float* st    = (const float*)d_in[15];
  const float* en    = (const float*)d_in[16];

  char* wsb = (char*)d_ws;
  float* em_f = (float*)wsb;                                   //  6,553,600 B
  float* em_b = (float*)(wsb + 6553600);                       //  6,553,600 B
  float* gold = (float*)(wsb + 13107200);                      //        512 B
  float* ab   = (float*)(wsb + 13107712);                      //     25,600 B
  unsigned short* gin16 = (unsigned short*)(wsb + 13133312);   // 104,857,600 B
  const size_t need = 117990912ULL;

  if (ws_size >= need) {
    gin_mfma<<<512, 256, 0, stream>>>(tok, emb, wif, bif, bhf, wib, bib, bhb, gin16);
    lstm_scan6<<<256, 512, 0, stream>>>(gin16, whf, whb, wtag, btag, em_f, em_b);
  } else {
    unsigned short* hc16 = (unsigned short*)(wsb + 13133312);
    hipMemsetAsync(em_b, 0, 6553600, stream);
    lstm_scan_fb<<<256, 512, 0, stream>>>(tok, emb, wif, whf, bif, bhf,
                                          wib, whb, bib, bhb, hc16);
    emis2<<<1024, 256, 0, stream>>>(hc16, wtag, btag, em_f);
  }
  crf_scan5<<<256, 128, 0, stream>>>(em_f, em_b, tags, lens, trans, st, en, ab, gold);
  crf_final<<<1, 128, 0, stream>>>(ab, gold, (float*)d_out);
}